// Round 2
// baseline (104.806 us; speedup 1.0000x reference)
//
#include <hip/hip_runtime.h>
#include <cmath>

// NSAB_5420248727612: per-row sigmoid-moment reductions + 2x2 Newton solve.
// B=2048 rows, N=8192 cols fp32. Memory-bound floor ~11 us (64 MiB @ 6.3 TB/s).
// R1 change: specialize N=8192 — each thread owns exactly 8 float4s; load all
// 8 up front (8 outstanding global_load_dwordx4 per wave) to hide HBM latency,
// then run the 12-accumulator body purely on registers. Generic fallback kept.
// Final 2x2 solve in double (den is a cancellation-prone subtraction; once per
// row, free insurance).

#define THREADS 256

__device__ __forceinline__ float fast_exp2(float t) {
#if __has_builtin(__builtin_amdgcn_exp2f)
    return __builtin_amdgcn_exp2f(t);   // v_exp_f32
#else
    return exp2f(t);
#endif
}

__device__ __forceinline__ float fast_rcp(float t) {
#if __has_builtin(__builtin_amdgcn_rcpf)
    return __builtin_amdgcn_rcpf(t);    // v_rcp_f32 (~1 ulp)
#else
    return 1.0f / t;
#endif
}

struct Acc12 {
    float s, ss, sp, spx, q, qx, qx2, fsp, fspx, w, wx, wx2;
};

__device__ __forceinline__ void acc_elem(Acc12& A, float xx, float c1, float c0) {
    const float e   = fast_exp2(fmaf(c1, xx, c0));   // exp(-(a x + b))
    const float s   = fast_rcp(1.0f + e);            // sigmoid
    const float sp  = s * (1.0f - s);                 // f'
    const float spp = sp * fmaf(-2.0f, s, 1.0f);      // f''
    const float ssp = s * sp;
    const float w   = fmaf(s, spp, sp * sp);          // sp^2 + s*spp
    const float x2  = xx * xx;
    A.s   += s;
    A.ss   = fmaf(s,   s,   A.ss);
    A.sp  += sp;
    A.spx  = fmaf(sp,  xx,  A.spx);
    A.q   += spp;
    A.qx   = fmaf(spp, xx,  A.qx);
    A.qx2  = fmaf(spp, x2,  A.qx2);
    A.fsp += ssp;
    A.fspx = fmaf(ssp, xx,  A.fspx);
    A.w   += w;
    A.wx   = fmaf(w,   xx,  A.wx);
    A.wx2  = fmaf(w,   x2,  A.wx2);
}

template <bool FIXED8192>
__global__ __launch_bounds__(THREADS) void nsab_kernel(
    const float* __restrict__ x,
    const float* __restrict__ a,
    const float* __restrict__ b,
    const float* __restrict__ meanp,
    const float* __restrict__ varp,
    float* __restrict__ out,
    int B, int N)
{
    const int row = blockIdx.x;
    const int tid = threadIdx.x;

    const float av = a[row];
    const float bv = b[row];
    // s = 1/(1+exp(-(a*x+b))) = 1/(1+exp2(c1*x+c0))
    const float LOG2E = 1.4426950408889634f;
    const float c1 = -av * LOG2E;
    const float c0 = -bv * LOG2E;

    const float4* __restrict__ xr = (const float4*)(x + (size_t)row * (size_t)N);

    Acc12 A = {0.f,0.f,0.f,0.f,0.f,0.f,0.f,0.f,0.f,0.f,0.f,0.f};

    if (FIXED8192) {
        // 8192/4 = 2048 float4s, 256 threads -> exactly 8 per thread.
        // Load all 8 first: 8 outstanding dwordx4 loads per wave.
        float4 v[8];
        #pragma unroll
        for (int k = 0; k < 8; ++k)
            v[k] = xr[tid + THREADS * k];
        #pragma unroll
        for (int k = 0; k < 8; ++k) {
            acc_elem(A, v[k].x, c1, c0);
            acc_elem(A, v[k].y, c1, c0);
            acc_elem(A, v[k].z, c1, c0);
            acc_elem(A, v[k].w, c1, c0);
        }
    } else {
        const int nvec = N >> 2;
        for (int i = tid; i < nvec; i += THREADS) {
            float4 v = xr[i];
            acc_elem(A, v.x, c1, c0);
            acc_elem(A, v.y, c1, c0);
            acc_elem(A, v.z, c1, c0);
            acc_elem(A, v.w, c1, c0);
        }
    }

    float acc[12] = {A.s, A.ss, A.sp, A.spx, A.q, A.qx, A.qx2,
                     A.fsp, A.fspx, A.w, A.wx, A.wx2};

    // 64-lane wave butterfly reduce
    #pragma unroll
    for (int i = 0; i < 12; ++i) {
        float v = acc[i];
        #pragma unroll
        for (int off = 32; off > 0; off >>= 1)
            v += __shfl_down(v, off, 64);
        acc[i] = v;
    }

    __shared__ float part[THREADS / 64][12];
    const int wave = tid >> 6;
    const int lane = tid & 63;
    if (lane == 0) {
        #pragma unroll
        for (int i = 0; i < 12; ++i) part[wave][i] = acc[i];
    }
    __syncthreads();

    if (tid == 0) {
        double S[12];
        #pragma unroll
        for (int i = 0; i < 12; ++i)
            S[i] = (double)part[0][i] + (double)part[1][i]
                 + (double)part[2][i] + (double)part[3][i];

        const double invN = 1.0 / (double)N;
        const double fm       = S[0]  * invN;
        const double mff      = S[1]  * invN;
        const double dem_db   = S[2]  * invN;
        const double dem_da   = S[3]  * invN;
        const double d2em_db2 = S[4]  * invN;
        const double d2em_dab = S[5]  * invN;
        const double d2em_da2 = S[6]  * invN;
        const double m_fdfb   = S[7]  * invN;
        const double m_fdfa   = S[8]  * invN;
        const double m_w      = S[9]  * invN;
        const double m_wx     = S[10] * invN;
        const double m_wx2    = S[11] * invN;

        const double mv = (double)meanp[row];
        const double vv = (double)varp[row];

        const double em = fm - mv;
        const double ev = mff - fm * fm - vv;
        const double dev_da = 2.0 * (m_fdfa - fm * dem_da);
        const double dev_db = 2.0 * (m_fdfb - fm * dem_db);
        const double d2ev_da2 = 2.0 * (m_wx2 - dem_da * dem_da - fm * d2em_da2);
        const double d2ev_dab = 2.0 * (m_wx  - dem_da * dem_db - fm * d2em_dab);
        const double d2ev_db2 = 2.0 * (m_w   - dem_db * dem_db - fm * d2em_db2);

        const double dl_da = 2.0 * (em * dem_da + ev * dev_da);
        const double dl_db = 2.0 * (em * dem_db + ev * dev_db);
        const double d2l_da2 = 2.0 * (dem_da * dem_da + em * d2em_da2
                                    + dev_da * dev_da + ev * d2ev_da2);
        const double d2l_dab = 2.0 * (dem_da * dem_db + em * d2em_dab
                                    + dev_da * dev_db + ev * d2ev_dab);
        const double d2l_db2 = 2.0 * (dem_db * dem_db + em * d2em_db2
                                    + dev_db * dev_db + ev * d2ev_db2);

        const double den = d2l_da2 * d2l_db2 - d2l_dab * d2l_dab;
        const double na = (dl_da * d2l_db2 - dl_db * d2l_dab) / den;
        const double nb = (dl_db * d2l_da2 - dl_da * d2l_dab) / den;

        out[row]     = (float)na;
        out[B + row] = (float)nb;
    }
}

extern "C" void kernel_launch(void* const* d_in, const int* in_sizes, int n_in,
                              void* d_out, int out_size, void* d_ws, size_t ws_size,
                              hipStream_t stream) {
    const float* x    = (const float*)d_in[0];
    const float* a    = (const float*)d_in[1];
    const float* b    = (const float*)d_in[2];
    const float* mean = (const float*)d_in[3];
    const float* var  = (const float*)d_in[4];
    const int B = in_sizes[1];            // a is (B,1)
    const int N = in_sizes[0] / B;        // x is (B,N)
    float* out = (float*)d_out;

    if (N == 8192) {
        nsab_kernel<true><<<dim3(B), dim3(THREADS), 0, stream>>>(x, a, b, mean, var, out, B, N);
    } else {
        nsab_kernel<false><<<dim3(B), dim3(THREADS), 0, stream>>>(x, a, b, mean, var, out, B, N);
    }
}